// Round 4
// baseline (126.473 us; speedup 1.0000x reference)
//
#include <hip/hip_runtime.h>

#define W      512
#define IMG    (512 * 512)
#define NB     16
#define NPIX   (NB * IMG)
#define TILE_H 8
#define APRON  3
#define LROWS  (TILE_H + 2 * APRON)   // 14
#define BLOCK  256
#define NEDT   1024                   // 16 images x 64 tiles
#define NLOSS  1024                   // 16 images x 64 slabs

struct WS {
    unsigned int vmax[16];        // memset 0 each launch
    float Scol[16 * 512];         // memset 0 each launch (atomicAdd target)
    float rows[16 * 512];         // w_edt[b, h=b, y] — fully written by EDT blocks
    float partial[NLOSS][8];      // per-loss-block partials {pt, p, st, C, A}
};

// Fused kernel: even blocks do exact EDT (rows + per-image max d^2), odd blocks
// do the EDT-independent loss sums. Roles are block-uniform, fully independent.
__global__ __launch_bounds__(BLOCK) void fused_kernel(const float* __restrict__ inp,
                                                      const float* __restrict__ tgt,
                                                      WS* __restrict__ ws) {
    __shared__ unsigned long long zm[LROWS][10];  // bit-mask, cols 1..8 data, 0/9 sentinel
    __shared__ unsigned short Dd[LROWS][W];       // 14 KB row-profile distances
    __shared__ float colsum[128][4];              // loss-role column partials
    __shared__ float sred[BLOCK / 64][8];         // cross-wave reductions

    int blk  = blockIdx.x;
    int role = blk & 1;
    int id   = blk >> 1;          // 0..1023 per role
    int b    = id >> 6;
    int tid  = threadIdx.x;
    int wave = tid >> 6, lane = tid & 63;

    if (role == 0) {
        // ================= EDT role =================
        int tile = id & 63;
        int h0   = tile * TILE_H;
        const float* img = tgt + (size_t)b * IMG;

        // Phase 1: pack zeros-mask (1 bit/px) via ballot; coalesced 256B loads.
        for (int wi = wave; wi < LROWS * 8; wi += 4) {
            int lr = wi >> 3, wc = wi & 7;
            int gh = h0 - APRON + lr;
            unsigned long long m = 0ULL;
            if (gh >= 0 && gh < W) {
                float v = img[(gh << 9) + (wc << 6) + lane];
                m = __ballot(v == 0.0f);
            }
            if (lane == 0) zm[lr][wc + 1] = m;
        }
        if (tid < LROWS) { zm[tid][0] = 0ULL; zm[tid][9] = 0ULL; }
        __syncthreads();

        // Phase 2: 1-D row profiles, branch-free bit windows.
        for (int u = wave; u < LROWS * 8; u += 4) {
            int lr = u >> 3, wc = u & 7;
            unsigned long long Wm = zm[lr][wc];
            unsigned long long Wc = zm[lr][wc + 1];
            unsigned long long Wp = zm[lr][wc + 2];
            int off = lane;
            unsigned long long wr = (Wc >> off) | (off ? (Wp << (64 - off)) : 0ULL);
            int dr = wr ? __builtin_ctzll(wr) : 1000;
            unsigned long long vl = off ? ((Wc << (64 - off)) | (Wm >> off)) : Wm;
            int dl = vl ? (1 + __builtin_clzll(vl)) : 1000;
            Dd[lr][(wc << 6) + lane] = (unsigned short)min(min(dr, dl), 1000);
        }
        __syncthreads();

        // Phase 3: 7-term combine; exact iff best <= 16 (|dh|>=4 => d^2>=16).
        unsigned int bmax = 0;
        for (int k = 0; k < TILE_H * W / BLOCK; ++k) {   // 16 px/thread
            int p  = tid + (k << 8);
            int y  = p & (W - 1);
            int hl = p >> 9;
            int lr = hl + APRON;
            int d0 = Dd[lr][y];
            int a1 = Dd[lr - 1][y], b1 = Dd[lr + 1][y];
            int a2 = Dd[lr - 2][y], b2 = Dd[lr + 2][y];
            int a3 = Dd[lr - 3][y], b3 = Dd[lr + 3][y];
            int best = d0 * d0;
            best = min(best, 1 + a1 * a1); best = min(best, 1 + b1 * b1);
            best = min(best, 4 + a2 * a2); best = min(best, 4 + b2 * b2);
            best = min(best, 9 + a3 * a3); best = min(best, 9 + b3 * b3);
            if (best > 16) {   // P ~= 2^-46 per px — exactness fallback
                int h = h0 + hl;
                int nb = 100000000;   // reference BIG when image has no zeros
                for (int gh = 0; gh < W; ++gh) {
                    int dhh = gh - h, dh2 = dhh * dhh;
                    if (dh2 >= nb) continue;
                    const float* rp = img + (gh << 9);
                    for (int yy = 0; yy < W; ++yy)
                        if (rp[yy] == 0.0f) {
                            int dx = yy - y;
                            nb = min(nb, dh2 + dx * dx);
                        }
                }
                best = nb;
            }
            if (h0 + hl == b) ws->rows[(b << 9) + y] = sqrtf((float)best);
            bmax = max(bmax, (unsigned int)best);
        }
        #pragma unroll
        for (int o = 32; o > 0; o >>= 1)
            bmax = max(bmax, (unsigned int)__shfl_down((int)bmax, o));
        if (lane == 0) sred[wave][0] = __uint_as_float(bmax);
        __syncthreads();
        if (tid == 0) {
            unsigned int bm = __float_as_uint(sred[0][0]);
            #pragma unroll
            for (int i = 1; i < BLOCK / 64; ++i) bm = max(bm, __float_as_uint(sred[i][0]));
            atomicMax(&ws->vmax[b], bm);
        }
    } else {
        // ================= loss role =================
        int slab = id & 63;
        const float4* x4 = (const float4*)inp;
        const float4* t4 = (const float4*)tgt;
        int c4 = tid & 127;        // float4-column
        int r0 = tid >> 7;         // 0/1
        int base = (b << 16) + (slab << 10);
        float cs0 = 0.f, cs1 = 0.f, cs2 = 0.f, cs3 = 0.f;
        float A = 0.f, C = 0.f, pt = 0.f, pp = 0.f, st = 0.f;
        #pragma unroll
        for (int k = 0; k < 4; ++k) {
            int rr = r0 + (k << 1);
            int i = base + (rr << 7) + c4;
            float4 xv = x4[i];
            float4 tv = t4[i];
            {
                float d = xv.x - tv.x, dd = d * d; C += dd;
                float td2 = tv.x * dd; A += td2; cs0 += td2;
                float pr = 1.0f / (1.0f + __expf(-xv.x));
                pt += pr * tv.x; pp += pr; st += tv.x;
            }
            {
                float d = xv.y - tv.y, dd = d * d; C += dd;
                float td2 = tv.y * dd; A += td2; cs1 += td2;
                float pr = 1.0f / (1.0f + __expf(-xv.y));
                pt += pr * tv.y; pp += pr; st += tv.y;
            }
            {
                float d = xv.z - tv.z, dd = d * d; C += dd;
                float td2 = tv.z * dd; A += td2; cs2 += td2;
                float pr = 1.0f / (1.0f + __expf(-xv.z));
                pt += pr * tv.z; pp += pr; st += tv.z;
            }
            {
                float d = xv.w - tv.w, dd = d * d; C += dd;
                float td2 = tv.w * dd; A += td2; cs3 += td2;
                float pr = 1.0f / (1.0f + __expf(-xv.w));
                pt += pr * tv.w; pp += pr; st += tv.w;
            }
        }
        // column sums -> global Scol (atomicAdd; 512 atomics/block)
        if (r0 == 1) { colsum[c4][0] = cs0; colsum[c4][1] = cs1;
                       colsum[c4][2] = cs2; colsum[c4][3] = cs3; }
        __syncthreads();
        if (r0 == 0) {
            atomicAdd(&ws->Scol[(b << 9) + (c4 << 2) + 0], cs0 + colsum[c4][0]);
            atomicAdd(&ws->Scol[(b << 9) + (c4 << 2) + 1], cs1 + colsum[c4][1]);
            atomicAdd(&ws->Scol[(b << 9) + (c4 << 2) + 2], cs2 + colsum[c4][2]);
            atomicAdd(&ws->Scol[(b << 9) + (c4 << 2) + 3], cs3 + colsum[c4][3]);
        }
        // block-reduce the 5 scalars
        #pragma unroll
        for (int o = 32; o > 0; o >>= 1) {
            pt += __shfl_down(pt, o); pp += __shfl_down(pp, o);
            st += __shfl_down(st, o); C  += __shfl_down(C, o);
            A  += __shfl_down(A, o);
        }
        if (lane == 0) { sred[wave][0] = pt; sred[wave][1] = pp; sred[wave][2] = st;
                         sred[wave][3] = C;  sred[wave][4] = A; }
        __syncthreads();
        if (tid == 0) {
            float a0 = 0, a1 = 0, a2 = 0, a3 = 0, a4 = 0;
            #pragma unroll
            for (int i = 0; i < BLOCK / 64; ++i) {
                a0 += sred[i][0]; a1 += sred[i][1]; a2 += sred[i][2];
                a3 += sred[i][3]; a4 += sred[i][4];
            }
            float* pr = ws->partial[id];
            pr[0] = a0; pr[1] = a1; pr[2] = a2; pr[3] = a3; pr[4] = a4;
        }
    }
}

// Finalize: reduce partials + rows·Scol dot + per-image v_b*A_b, emit 2 scalars.
__global__ __launch_bounds__(BLOCK) void finalize_kernel(const WS* __restrict__ ws,
                                                         float* __restrict__ out) {
    int tid = threadIdx.x;
    double pt = 0, pp = 0, st = 0, C = 0;
    for (int j = tid; j < NLOSS; j += BLOCK) {
        const float* pr = ws->partial[j];
        pt += pr[0]; pp += pr[1]; st += pr[2]; C += pr[3];
    }
    // vA: 16 threads/image, 4 partials each
    int ib = tid >> 4;
    double Ab = 0;
    {
        int k0 = (tid & 15) * 4;
        #pragma unroll
        for (int j = 0; j < 4; ++j) Ab += ws->partial[ib * 64 + k0 + j][4];
    }
    double vA = sqrt((double)ws->vmax[ib]) * Ab;
    // dot(rows, Scol) over 8192 elems
    double Bs = 0;
    for (int j = tid; j < 16 * 512; j += BLOCK)
        Bs += (double)ws->rows[j] * (double)ws->Scol[j];

    #pragma unroll
    for (int o = 32; o > 0; o >>= 1) {
        pt += __shfl_down(pt, o); pp += __shfl_down(pp, o);
        st += __shfl_down(st, o); C  += __shfl_down(C, o);
        vA += __shfl_down(vA, o); Bs += __shfl_down(Bs, o);
    }
    __shared__ double sh[BLOCK / 64][6];
    int lane = tid & 63, wid = tid >> 6;
    if (lane == 0) { sh[wid][0] = pt; sh[wid][1] = pp; sh[wid][2] = st;
                     sh[wid][3] = C;  sh[wid][4] = vA; sh[wid][5] = Bs; }
    __syncthreads();
    if (tid == 0) {
        double a0 = 0, a1 = 0, a2 = 0, a3 = 0, a4 = 0, a5 = 0;
        #pragma unroll
        for (int i = 0; i < BLOCK / 64; ++i) {
            a0 += sh[i][0]; a1 += sh[i][1]; a2 += sh[i][2];
            a3 += sh[i][3]; a4 += sh[i][4]; a5 += sh[i][5];
        }
        double wsum = a4 - a5 + 0.001 * a3;   // v·A - rows·Scol + eps·C
        out[0] = (float)(0.6 * (wsum / (double)NPIX));
        out[1] = (float)(1.0 - (2.0 * a0 + 1e-6) / (a1 + a2 + 1e-6));
    }
}

extern "C" void kernel_launch(void* const* d_in, const int* in_sizes, int n_in,
                              void* d_out, int out_size, void* d_ws, size_t ws_size,
                              hipStream_t stream) {
    const float* inp = (const float*)d_in[0];
    const float* tgt = (const float*)d_in[1];
    float* out = (float*)d_out;
    WS* ws = (WS*)d_ws;

    // zero vmax + Scol (contiguous at struct front): 64 + 32768 bytes
    hipMemsetAsync(d_ws, 0, sizeof(unsigned int) * 16 + sizeof(float) * 16 * 512, stream);
    fused_kernel<<<NEDT + NLOSS, BLOCK, 0, stream>>>(inp, tgt, ws);
    finalize_kernel<<<1, BLOCK, 0, stream>>>(ws, out);
}